// Round 1
// baseline (184.487 us; speedup 1.0000x reference)
//
#include <hip/hip_runtime.h>

#define NATOMS 10000
#define KNB 32
#define FD 128
#define NRBF 300

typedef short short8 __attribute__((ext_vector_type(8)));
typedef float f32x4 __attribute__((ext_vector_type(4)));

__device__ __forceinline__ unsigned short f2bf(float f) {
    unsigned int u = __float_as_uint(f);
    u = (u + 0x7fffu + ((u >> 16) & 1u)) >> 16;
    return (unsigned short)u;
}

__device__ __forceinline__ float sspf(float x) {
    // softplus(x) - ln2, numerically stable
    return fmaxf(x, 0.f) + __logf(1.f + __expf(-fabsf(x))) - 0.69314718055994531f;
}

// Pack W_cf1 (300x128 f32) -> bf16 [10][4][128][8] (k = kc*32+g*8+j, zero-pad k>=300)
// Pack W_cf2 (128x128 f32) -> bf16 [4][4][128][8]
__global__ __launch_bounds__(256) void prep_pack(const float* __restrict__ Wcf1,
                                                 const float* __restrict__ Wcf2,
                                                 unsigned short* __restrict__ w1p,
                                                 unsigned short* __restrict__ w2p) {
    int idx = blockIdx.x * 256 + threadIdx.x;
    if (idx < 40960) {
        int j = idx & 7, c = (idx >> 3) & 127, g = (idx >> 10) & 3, kc = idx >> 12;
        int k = kc * 32 + g * 8 + j;
        float v = (k < NRBF) ? Wcf1[k * FD + c] : 0.f;
        w1p[idx] = f2bf(v);
    } else if (idx < 57344) {
        int t = idx - 40960;
        int j = t & 7, c = (t >> 3) & 127, g = (t >> 10) & 3, kc = t >> 12;
        int k = kc * 32 + g * 8 + j;
        w2p[t] = f2bf(Wcf2[k * FD + c]);
    }
}

// Y[r][:] = act(X[r][:] @ W + b) (+ resid);  16 rows per block, W staged in LDS.
__global__ __launch_bounds__(256) void linear16(const float* __restrict__ X,
                                                const float* __restrict__ W,
                                                const float* __restrict__ bias,
                                                const float* __restrict__ resid,
                                                float* __restrict__ Y, int act) {
    __shared__ float Wl[FD * FD];
    __shared__ float Al[16][FD];
    const int tid = threadIdx.x;
    const int r0 = blockIdx.x * 16;
    for (int idx = tid; idx < FD * FD / 4; idx += 256)
        ((float4*)Wl)[idx] = ((const float4*)W)[idx];
    for (int idx = tid; idx < 16 * FD / 4; idx += 256)
        ((float4*)&Al[0][0])[idx] = ((const float4*)(X + (size_t)r0 * FD))[idx];
    __syncthreads();
#pragma unroll
    for (int tt = 0; tt < 2; ++tt) {
        int id = tid + 256 * tt;
        int row = id >> 5;
        int c4 = (id & 31) * 4;
        float4 b4 = *(const float4*)&bias[c4];
        float ax = b4.x, ay = b4.y, az = b4.z, aw = b4.w;
#pragma unroll 4
        for (int k = 0; k < FD; ++k) {
            float a = Al[row][k];
            float4 wv = *(const float4*)&Wl[k * FD + c4];
            ax += a * wv.x; ay += a * wv.y; az += a * wv.z; aw += a * wv.w;
        }
        if (act) { ax = sspf(ax); ay = sspf(ay); az = sspf(az); aw = sspf(aw); }
        int o = (r0 + row) * FD + c4;
        if (resid) {
            float4 r4 = *(const float4*)&resid[o];
            ax += r4.x; ay += r4.y; az += r4.z; aw += r4.w;
        }
        float4 o4 = {ax, ay, az, aw};
        *(float4*)&Y[o] = o4;
    }
}

// The fused cfconv: 4 atoms (128 edges) per block, 4 waves, wave w <-> atom i0+w.
__global__ __launch_bounds__(256) void conv_kernel(
    const float* __restrict__ xyz, const int* __restrict__ src,
    const float* __restrict__ mask, const float* __restrict__ centers,
    const float* __restrict__ pre, const unsigned short* __restrict__ w1p,
    const unsigned short* __restrict__ w2p, float* __restrict__ conv) {
    __shared__ float cent[320];
    __shared__ float dL[128];
    __shared__ float mL[128];
    __shared__ int   sL[128];
    __shared__ unsigned short w1c[4][128][8];        // one 32-k chunk of packed W_cf1 (8KB)
    __shared__ unsigned short w2l[4][4][128][8];     // all packed W_cf2 (32KB)
    __shared__ unsigned short A2[128][136];          // ssp(GEMM1) as bf16, padded stride

    const int tid = threadIdx.x;
    const int i0 = blockIdx.x * 4;

    for (int idx = tid; idx < 320; idx += 256)
        cent[idx] = (idx < NRBF) ? centers[idx] : 1e8f;   // pad -> exp(-inf)=0
    if (tid < 128) {
        int al = tid >> 5, kk = tid & 31;
        int i = i0 + al;
        int s = src[i * KNB + kk];
        float dx = xyz[3 * s]     - xyz[3 * i];
        float dy = xyz[3 * s + 1] - xyz[3 * i + 1];
        float dz = xyz[3 * s + 2] - xyz[3 * i + 2];
        dL[tid] = sqrtf(dx * dx + dy * dy + dz * dz);
        mL[tid] = mask[i * KNB + kk];
        sL[tid] = s;
    }
    {
        const float4* s4 = (const float4*)w2p;
        float4* d4 = (float4*)&w2l[0][0][0][0];
        for (int idx = tid; idx < 2048; idx += 256) d4[idx] = s4[idx];
    }
    __syncthreads();

    const int w = tid >> 6;
    const int lane = tid & 63;
    const int g = lane >> 4;
    const int c16 = lane & 15;

    const float d0 = dL[w * 32 + c16];
    const float d1 = dL[w * 32 + 16 + c16];

    f32x4 acc[2][8];
#pragma unroll
    for (int a = 0; a < 2; ++a)
#pragma unroll
        for (int b = 0; b < 8; ++b) acc[a][b] = (f32x4){0.f, 0.f, 0.f, 0.f};

    // ---- GEMM1: C1[128 edges][128] = rbf[128][320] @ W_cf1[320][128] ----
    for (int kc = 0; kc < 10; ++kc) {
        __syncthreads();  // previous chunk's reads complete
        {
            const float4* s4 = (const float4*)(w1p + kc * 4096);
            float4* d4 = (float4*)&w1c[0][0][0];
            for (int idx = tid; idx < 512; idx += 256) d4[idx] = s4[idx];
        }
        // generate a-frags in-register while staging is in flight
        short8 a0, a1;
#pragma unroll
        for (int j = 0; j < 8; ++j) {
            float cc = cent[kc * 32 + g * 8 + j];
            float t0 = d0 - cc;
            float t1 = d1 - cc;
            a0[j] = (short)f2bf(__expf(-10.f * t0 * t0));
            a1[j] = (short)f2bf(__expf(-10.f * t1 * t1));
        }
        __syncthreads();  // chunk visible
#pragma unroll
        for (int nb = 0; nb < 8; ++nb) {
            short8 b = *(const short8*)&w1c[g][nb * 16 + c16][0];
            acc[0][nb] = __builtin_amdgcn_mfma_f32_16x16x32_bf16(a0, b, acc[0][nb], 0, 0, 0);
            acc[1][nb] = __builtin_amdgcn_mfma_f32_16x16x32_bf16(a1, b, acc[1][nb], 0, 0, 0);
        }
    }

    // ssp -> bf16 A2 tile
#pragma unroll
    for (int mr = 0; mr < 2; ++mr)
#pragma unroll
        for (int nb = 0; nb < 8; ++nb)
#pragma unroll
            for (int q = 0; q < 4; ++q) {
                int row = w * 32 + mr * 16 + 4 * g + q;
                A2[row][nb * 16 + c16] = f2bf(sspf(acc[mr][nb][q]));
            }
    __syncthreads();

    // ---- GEMM2: C2 = A2 @ W_cf2 ----
    f32x4 acc2[2][8];
#pragma unroll
    for (int a = 0; a < 2; ++a)
#pragma unroll
        for (int b = 0; b < 8; ++b) acc2[a][b] = (f32x4){0.f, 0.f, 0.f, 0.f};

#pragma unroll
    for (int kc = 0; kc < 4; ++kc) {
        short8 a0 = *(const short8*)&A2[w * 32 + c16][kc * 32 + g * 8];
        short8 a1 = *(const short8*)&A2[w * 32 + 16 + c16][kc * 32 + g * 8];
#pragma unroll
        for (int nb = 0; nb < 8; ++nb) {
            short8 b = *(const short8*)&w2l[kc][g][nb * 16 + c16][0];
            acc2[0][nb] = __builtin_amdgcn_mfma_f32_16x16x32_bf16(a0, b, acc2[0][nb], 0, 0, 0);
            acc2[1][nb] = __builtin_amdgcn_mfma_f32_16x16x32_bf16(a1, b, acc2[1][nb], 0, 0, 0);
        }
    }

    // ssp -> * pre[src] * mask -> reduce over 32 edges of this wave's atom
    float s[8] = {0.f, 0.f, 0.f, 0.f, 0.f, 0.f, 0.f, 0.f};
#pragma unroll
    for (int mr = 0; mr < 2; ++mr)
#pragma unroll
        for (int q = 0; q < 4; ++q) {
            int row = w * 32 + mr * 16 + 4 * g + q;
            int sr = sL[row];
            float mm = mL[row];
            const float* prow = pre + (size_t)sr * FD;
#pragma unroll
            for (int nb = 0; nb < 8; ++nb) {
                float f = sspf(acc2[mr][nb][q]);
                s[nb] += f * prow[nb * 16 + c16] * mm;
            }
        }
#pragma unroll
    for (int nb = 0; nb < 8; ++nb) {
        s[nb] += __shfl_xor(s[nb], 16);
        s[nb] += __shfl_xor(s[nb], 32);
    }
    if (g == 0) {
        int atom = i0 + w;
#pragma unroll
        for (int nb = 0; nb < 8; ++nb)
            conv[atom * FD + nb * 16 + c16] = s[nb];
    }
}

extern "C" void kernel_launch(void* const* d_in, const int* in_sizes, int n_in,
                              void* d_out, int out_size, void* d_ws, size_t ws_size,
                              hipStream_t stream) {
    const float* xyz     = (const float*)d_in[0];
    const float* atomic  = (const float*)d_in[1];
    const float* mask    = (const float*)d_in[2];
    const int*   src     = (const int*)d_in[3];
    const float* W_pre   = (const float*)d_in[4];
    const float* b_pre   = (const float*)d_in[5];
    const float* W_cf1   = (const float*)d_in[6];
    const float* W_cf2   = (const float*)d_in[7];
    const float* W_post1 = (const float*)d_in[8];
    const float* b_post1 = (const float*)d_in[9];
    const float* W_post2 = (const float*)d_in[10];
    const float* b_post2 = (const float*)d_in[11];
    const float* centers = (const float*)d_in[12];
    float* out = (float*)d_out;

    float* pre  = (float*)d_ws;                       // N*F f32
    float* conv = pre + NATOMS * FD;                  // N*F f32
    unsigned short* w1p = (unsigned short*)(conv + NATOMS * FD);  // 40960 bf16
    unsigned short* w2p = w1p + 40960;                // 16384 bf16
    float* tmp = pre;                                 // pre is dead after conv_kernel

    prep_pack<<<224, 256, 0, stream>>>(W_cf1, W_cf2, w1p, w2p);
    linear16<<<625, 256, 0, stream>>>(atomic, W_pre, b_pre, nullptr, pre, 0);
    conv_kernel<<<2500, 256, 0, stream>>>(xyz, src, mask, centers, pre, w1p, w2p, conv);
    linear16<<<625, 256, 0, stream>>>(conv, W_post1, b_post1, nullptr, tmp, 1);
    linear16<<<625, 256, 0, stream>>>(tmp, W_post2, b_post2, atomic, out, 0);
}